// Round 1
// baseline (187.084 us; speedup 1.0000x reference)
//
#include <hip/hip_runtime.h>

// 3D LUT trilinear apply — round 5 resubmit (prior bench died to container
// infra failure, no counters produced; source unchanged).
// R3 post-mortem: 97 us kernel. LDS gather fixed the L1 bottleneck
// (LDS ~12 us, VALU ~12 us). Limiter: HBM traffic — WRITE_SIZE 265 MiB
// vs 96 MiB output (2.7x write amplification), BW 3.8 TB/s (60% achievable).
// This round: (a) nontemporal loads/stores for the zero-reuse x/out streams,
// (b) software-pipelined grid-stride loop (prefetch next 3x float4),
// (c) LUT quantize folded into per-block LDS fill (drops pack dispatch+d_ws).

namespace {

constexpr int DIM    = 33;
constexpr int WH     = 1024 * 1024;     // 2^20
constexpr int BATCH  = 8;
constexpr int NPIX   = BATCH * WH;      // 8388608
constexpr int LUT_N  = DIM * DIM * DIM; // 35937

constexpr int BLOCKS  = 256;
constexpr int TPB     = 1024;
constexpr int NTHREAD = BLOCKS * TPB;        // 262144
constexpr int NGROUP  = NPIX / 4;            // 2097152 float4-pixel groups
constexpr int NITER   = NGROUP / NTHREAD;    // exactly 8

using f4 = __attribute__((ext_vector_type(4))) float;

__device__ __forceinline__ f4 nt_load4(const float* p) {
    return __builtin_nontemporal_load((const f4*)p);
}
__device__ __forceinline__ void nt_store4(float* p, f4 v) {
    __builtin_nontemporal_store(v, (f4*)p);
}

__device__ __forceinline__ void sample_one_lds(
    const unsigned int* lds_lut, float r, float g, float b,
    float& outR, float& outG, float& outB)
{
    const float inv_binsize = 32.0f / 1.0001f;
    float sr = r * inv_binsize;
    float sg = g * inv_binsize;
    float sb = b * inv_binsize;
    // x in [0,1) => scaled in [0, 31.9968): trunc == floor, idx+1 <= 32 in-bounds.
    int ir = (int)sr, ig = (int)sg, ib = (int)sb;
    float fr = sr - (float)ir;
    float fg = sg - (float)ig;
    float fb = sb - (float)ib;

    int base = ib * (DIM * DIM) + ig * DIM + ir;

    unsigned int p000 = lds_lut[base];
    unsigned int p100 = lds_lut[base + 1];
    unsigned int p010 = lds_lut[base + DIM];
    unsigned int p110 = lds_lut[base + DIM + 1];
    unsigned int p001 = lds_lut[base + DIM * DIM];
    unsigned int p101 = lds_lut[base + DIM * DIM + 1];
    unsigned int p011 = lds_lut[base + DIM * DIM + DIM];
    unsigned int p111 = lds_lut[base + DIM * DIM + DIM + 1];

    float w00 = (1.f - fg) * (1.f - fb);
    float w10 = fg * (1.f - fb);
    float w01 = (1.f - fg) * fb;
    float w11 = fg * fb;
    float w000 = (1.f - fr) * w00, w100 = fr * w00;
    float w010 = (1.f - fr) * w10, w110 = fr * w10;
    float w001 = (1.f - fr) * w01, w101 = fr * w01;
    float w011 = (1.f - fr) * w11, w111 = fr * w11;

    float accR, accG, accB;
    accR  = w000 * (float)(p000 & 1023u);
    accG  = w000 * (float)((p000 >> 10) & 1023u);
    accB  = w000 * (float)((p000 >> 20) & 1023u);
    accR += w100 * (float)(p100 & 1023u);
    accG += w100 * (float)((p100 >> 10) & 1023u);
    accB += w100 * (float)((p100 >> 20) & 1023u);
    accR += w010 * (float)(p010 & 1023u);
    accG += w010 * (float)((p010 >> 10) & 1023u);
    accB += w010 * (float)((p010 >> 20) & 1023u);
    accR += w110 * (float)(p110 & 1023u);
    accG += w110 * (float)((p110 >> 10) & 1023u);
    accB += w110 * (float)((p110 >> 20) & 1023u);
    accR += w001 * (float)(p001 & 1023u);
    accG += w001 * (float)((p001 >> 10) & 1023u);
    accB += w001 * (float)((p001 >> 20) & 1023u);
    accR += w101 * (float)(p101 & 1023u);
    accG += w101 * (float)((p101 >> 10) & 1023u);
    accB += w101 * (float)((p101 >> 20) & 1023u);
    accR += w011 * (float)(p011 & 1023u);
    accG += w011 * (float)((p011 >> 10) & 1023u);
    accB += w011 * (float)((p011 >> 20) & 1023u);
    accR += w111 * (float)(p111 & 1023u);
    accG += w111 * (float)((p111 >> 10) & 1023u);
    accB += w111 * (float)((p111 >> 20) & 1023u);

    const float inv1023 = 1.0f / 1023.0f;
    outR = accR * inv1023;
    outG = accG * inv1023;
    outB = accB * inv1023;
}

__global__ __launch_bounds__(TPB, 1) void lut3d_lds_kernel(
    const float* __restrict__ lut, const float* __restrict__ x,
    float* __restrict__ out)
{
    __shared__ unsigned int lds_lut[LUT_N]; // 143748 B -> 1 block/CU, 16 waves

    // stage: quantize f32 SoA LUT (global, L2/L3-hit) -> 10:10:10 u32 in LDS
    for (int i = threadIdx.x; i < LUT_N; i += TPB) {
        float r = lut[i];
        float g = lut[LUT_N + i];
        float b = lut[2 * LUT_N + i];
        unsigned int qr = (unsigned int)__float2int_rn(__saturatef(r) * 1023.0f);
        unsigned int qg = (unsigned int)__float2int_rn(__saturatef(g) * 1023.0f);
        unsigned int qb = (unsigned int)__float2int_rn(__saturatef(b) * 1023.0f);
        lds_lut[i] = qr | (qg << 10) | (qb << 20);
    }
    __syncthreads();

    int gid = blockIdx.x * TPB + threadIdx.x;

    // prologue load for iteration 0
    int P = gid * 4;
    int batch = P >> 20;
    int p = P & (WH - 1);
    const float* xb = x + (size_t)batch * 3 * WH + p;
    f4 r4 = nt_load4(xb);
    f4 g4 = nt_load4(xb + WH);
    f4 b4 = nt_load4(xb + 2 * WH);

#pragma unroll
    for (int it = 0; it < NITER; ++it) {
        // prefetch next iteration's inputs before the heavy compute
        f4 rn, gn, bn;
        int gnx = gid + NTHREAD;
        if (it + 1 < NITER) {
            int Pn = gnx * 4;
            int bn_ = Pn >> 20;
            int pn  = Pn & (WH - 1);
            const float* xn = x + (size_t)bn_ * 3 * WH + pn;
            rn = nt_load4(xn);
            gn = nt_load4(xn + WH);
            bn = nt_load4(xn + 2 * WH);
        }

        float* ob = out + (size_t)batch * 3 * WH + p;

        f4 oR, oG, oB;
#pragma unroll
        for (int l = 0; l < 4; ++l) {
            float tR, tG, tB;
            sample_one_lds(lds_lut, r4[l], g4[l], b4[l], tR, tG, tB);
            oR[l] = tR; oG[l] = tG; oB[l] = tB;
        }

        nt_store4(ob,          oR);
        nt_store4(ob + WH,     oG);
        nt_store4(ob + 2 * WH, oB);

        // rotate
        gid = gnx;
        P = gid * 4;
        batch = P >> 20;
        p = P & (WH - 1);
        r4 = rn; g4 = gn; b4 = bn;
    }
}

} // namespace

extern "C" void kernel_launch(void* const* d_in, const int* in_sizes, int n_in,
                              void* d_out, int out_size, void* d_ws, size_t ws_size,
                              hipStream_t stream) {
    const float* lut = (const float*)d_in[0];
    const float* x   = (const float*)d_in[1];
    float*       out = (float*)d_out;
    (void)d_ws; (void)ws_size;

    lut3d_lds_kernel<<<BLOCKS, TPB, 0, stream>>>(lut, x, out);
}

// Round 2
// 186.513 us; speedup vs baseline: 1.0031x; 1.0031x over previous
//
#include <hip/hip_runtime.h>

// 3D LUT trilinear apply — round 6.
// R5 result: dur_us 187.08 (== prev session best 186.3). rocprof top-5 = all
// harness poison fills (384 MiB @ ~61 us, 6.5 TB/s). Our kernel < 60 us
// (absent from top-5); timed path ~= 2 fills (~122 us, fixed) + kernel.
// Kernel floor = 192 MiB / 6.4 TB/s ~= 31 us -> ~25 us controllable headroom.
// R6 single-variable A/B: stores NT -> plain cached (keep NT loads, keep
// prefetch pipeline). Theory: nt no-allocate stores forfeit L2 write
// combining across the 3 plane streams -> partial-burst HBM writes.
// Predict: dur_us -> 160-172 if right; 185-189 if store path is clean.

namespace {

constexpr int DIM    = 33;
constexpr int WH     = 1024 * 1024;     // 2^20
constexpr int BATCH  = 8;
constexpr int NPIX   = BATCH * WH;      // 8388608
constexpr int LUT_N  = DIM * DIM * DIM; // 35937

constexpr int BLOCKS  = 256;
constexpr int TPB     = 1024;
constexpr int NTHREAD = BLOCKS * TPB;        // 262144
constexpr int NGROUP  = NPIX / 4;            // 2097152 float4-pixel groups
constexpr int NITER   = NGROUP / NTHREAD;    // exactly 8

using f4 = __attribute__((ext_vector_type(4))) float;

__device__ __forceinline__ f4 nt_load4(const float* p) {
    return __builtin_nontemporal_load((const f4*)p);
}
__device__ __forceinline__ void st4(float* p, f4 v) {
    *(f4*)p = v;   // plain cached store: full-line write-combine in L2
}

__device__ __forceinline__ void sample_one_lds(
    const unsigned int* lds_lut, float r, float g, float b,
    float& outR, float& outG, float& outB)
{
    const float inv_binsize = 32.0f / 1.0001f;
    float sr = r * inv_binsize;
    float sg = g * inv_binsize;
    float sb = b * inv_binsize;
    // x in [0,1) => scaled in [0, 31.9968): trunc == floor, idx+1 <= 32 in-bounds.
    int ir = (int)sr, ig = (int)sg, ib = (int)sb;
    float fr = sr - (float)ir;
    float fg = sg - (float)ig;
    float fb = sb - (float)ib;

    int base = ib * (DIM * DIM) + ig * DIM + ir;

    unsigned int p000 = lds_lut[base];
    unsigned int p100 = lds_lut[base + 1];
    unsigned int p010 = lds_lut[base + DIM];
    unsigned int p110 = lds_lut[base + DIM + 1];
    unsigned int p001 = lds_lut[base + DIM * DIM];
    unsigned int p101 = lds_lut[base + DIM * DIM + 1];
    unsigned int p011 = lds_lut[base + DIM * DIM + DIM];
    unsigned int p111 = lds_lut[base + DIM * DIM + DIM + 1];

    float w00 = (1.f - fg) * (1.f - fb);
    float w10 = fg * (1.f - fb);
    float w01 = (1.f - fg) * fb;
    float w11 = fg * fb;
    float w000 = (1.f - fr) * w00, w100 = fr * w00;
    float w010 = (1.f - fr) * w10, w110 = fr * w10;
    float w001 = (1.f - fr) * w01, w101 = fr * w01;
    float w011 = (1.f - fr) * w11, w111 = fr * w11;

    float accR, accG, accB;
    accR  = w000 * (float)(p000 & 1023u);
    accG  = w000 * (float)((p000 >> 10) & 1023u);
    accB  = w000 * (float)((p000 >> 20) & 1023u);
    accR += w100 * (float)(p100 & 1023u);
    accG += w100 * (float)((p100 >> 10) & 1023u);
    accB += w100 * (float)((p100 >> 20) & 1023u);
    accR += w010 * (float)(p010 & 1023u);
    accG += w010 * (float)((p010 >> 10) & 1023u);
    accB += w010 * (float)((p010 >> 20) & 1023u);
    accR += w110 * (float)(p110 & 1023u);
    accG += w110 * (float)((p110 >> 10) & 1023u);
    accB += w110 * (float)((p110 >> 20) & 1023u);
    accR += w001 * (float)(p001 & 1023u);
    accG += w001 * (float)((p001 >> 10) & 1023u);
    accB += w001 * (float)((p001 >> 20) & 1023u);
    accR += w101 * (float)(p101 & 1023u);
    accG += w101 * (float)((p101 >> 10) & 1023u);
    accB += w101 * (float)((p101 >> 20) & 1023u);
    accR += w011 * (float)(p011 & 1023u);
    accG += w011 * (float)((p011 >> 10) & 1023u);
    accB += w011 * (float)((p011 >> 20) & 1023u);
    accR += w111 * (float)(p111 & 1023u);
    accG += w111 * (float)((p111 >> 10) & 1023u);
    accB += w111 * (float)((p111 >> 20) & 1023u);

    const float inv1023 = 1.0f / 1023.0f;
    outR = accR * inv1023;
    outG = accG * inv1023;
    outB = accB * inv1023;
}

__global__ __launch_bounds__(TPB, 1) void lut3d_lds_kernel(
    const float* __restrict__ lut, const float* __restrict__ x,
    float* __restrict__ out)
{
    __shared__ unsigned int lds_lut[LUT_N]; // 143748 B -> 1 block/CU, 16 waves

    // stage: quantize f32 SoA LUT (global, L2/L3-hit) -> 10:10:10 u32 in LDS
    for (int i = threadIdx.x; i < LUT_N; i += TPB) {
        float r = lut[i];
        float g = lut[LUT_N + i];
        float b = lut[2 * LUT_N + i];
        unsigned int qr = (unsigned int)__float2int_rn(__saturatef(r) * 1023.0f);
        unsigned int qg = (unsigned int)__float2int_rn(__saturatef(g) * 1023.0f);
        unsigned int qb = (unsigned int)__float2int_rn(__saturatef(b) * 1023.0f);
        lds_lut[i] = qr | (qg << 10) | (qb << 20);
    }
    __syncthreads();

    int gid = blockIdx.x * TPB + threadIdx.x;

    // prologue load for iteration 0
    int P = gid * 4;
    int batch = P >> 20;
    int p = P & (WH - 1);
    const float* xb = x + (size_t)batch * 3 * WH + p;
    f4 r4 = nt_load4(xb);
    f4 g4 = nt_load4(xb + WH);
    f4 b4 = nt_load4(xb + 2 * WH);

#pragma unroll
    for (int it = 0; it < NITER; ++it) {
        // prefetch next iteration's inputs before the heavy compute
        f4 rn, gn, bn;
        int gnx = gid + NTHREAD;
        if (it + 1 < NITER) {
            int Pn = gnx * 4;
            int bn_ = Pn >> 20;
            int pn  = Pn & (WH - 1);
            const float* xn = x + (size_t)bn_ * 3 * WH + pn;
            rn = nt_load4(xn);
            gn = nt_load4(xn + WH);
            bn = nt_load4(xn + 2 * WH);
        }

        float* ob = out + (size_t)batch * 3 * WH + p;

        f4 oR, oG, oB;
#pragma unroll
        for (int l = 0; l < 4; ++l) {
            float tR, tG, tB;
            sample_one_lds(lds_lut, r4[l], g4[l], b4[l], tR, tG, tB);
            oR[l] = tR; oG[l] = tG; oB[l] = tB;
        }

        st4(ob,          oR);
        st4(ob + WH,     oG);
        st4(ob + 2 * WH, oB);

        // rotate
        gid = gnx;
        P = gid * 4;
        batch = P >> 20;
        p = P & (WH - 1);
        r4 = rn; g4 = gn; b4 = bn;
    }
}

} // namespace

extern "C" void kernel_launch(void* const* d_in, const int* in_sizes, int n_in,
                              void* d_out, int out_size, void* d_ws, size_t ws_size,
                              hipStream_t stream) {
    const float* lut = (const float*)d_in[0];
    const float* x   = (const float*)d_in[1];
    float*       out = (float*)d_out;
    (void)d_ws; (void)ws_size;

    lut3d_lds_kernel<<<BLOCKS, TPB, 0, stream>>>(lut, x, out);
}